// Round 1
// 466.828 us; speedup vs baseline: 1.0191x; 1.0191x over previous
//
#include <hip/hip_runtime.h>
#include <hip/hip_fp16.h>
#include <stdint.h>

// Linear4bit: out[t,n] = (sum_k a4[t,k]*w4[n,k]) * sx[t] * sw[n], fp16-rounded.
// Inputs arrive int32-widened: one int32 per *packed byte* (two nibbles).
// Round-7:
//  (1) gemm_i8_tb2: 512 threads / 8 waves (2Mx4N), per-wave 64x64 tile ->
//      acc 64 regs, total <=128/wave => 4 waves/SIMD (was 2). Same
//      triple-buffer distance-2 counted-vmcnt schedule (3 DMA/wave/stage,
//      vmcnt(3)), raw s_barrier, + setprio around MFMA clusters.
//  (2) unpack_tiles3: LDS-transpose preprocess. Loads are lane-contiguous
//      1KB/instruction (old version scattered 64x16B granules per VMEM op,
//      ~0.8 TB/s); stores are 512B runs. New per-cell k-permutation is the
//      same bijection for A and B => GEMM semantics unchanged.

#define T_DIM 4096
#define K_DIM 4096
#define N_DIM 11008
#define KP    2048              // packed bytes (= int32 elements) per row
#define BM 128
#define BN 256
#define STAGES 64               // BK = 64 (32 packed bytes per row per stage)
#define A_PANELS (T_DIM / BM)   // 32
#define B_PANELS (N_DIM / BN)   // 43
#define CHUNK_A 8192            // 4 cells x 128 rows x 16B
#define CHUNK_B 16384           // 4 cells x 256 rows x 16B
#define WS_A ((size_t)A_PANELS * STAGES * CHUNK_A)   // 16,777,216
#define WS_B ((size_t)B_PANELS * STAGES * CHUNK_B)   // 45,088,768
#define NA_BYTES ((size_t)T_DIM * KP)                // fallback packed sizes
#define NW_BYTES ((size_t)N_DIM * KP)

typedef __attribute__((ext_vector_type(4)))  int int32x4;
typedef __attribute__((ext_vector_type(16))) int int32x16;
typedef __attribute__((ext_vector_type(4)))  float floatx4;
typedef __attribute__((ext_vector_type(8)))  _Float16 f16x8;
typedef __attribute__((ext_vector_type(2)))  _Float16 f16x2;

__device__ __forceinline__ uint32_t pack4(int4 v) {
  return (uint32_t)(v.x & 0xFF) | ((uint32_t)(v.y & 0xFF) << 8) |
         ((uint32_t)(v.z & 0xFF) << 16) | ((uint32_t)(v.w & 0xFF) << 24);
}
// borrow-free SWAR nibble -> signed int8
__device__ __forceinline__ uint32_t nib_lo_s8(uint32_t p) {
  uint32_t t = (p & 0x0F0F0F0Fu) ^ 0x88888888u;
  return (t - 0x08080808u) ^ 0x80808080u;
}
__device__ __forceinline__ uint32_t nib_hi_s8(uint32_t p) {
  uint32_t t = ((p >> 4) & 0x0F0F0F0Fu) ^ 0x88888888u;
  return (t - 0x08080808u) ^ 0x80808080u;
}

// ------------- preprocess v3: coalesced loads + LDS transpose -------------
// Block = 32 rows x 16 stages of one operand image.
//   phase 1: 16 iters, each wave reads a contiguous 1KB row-slice (16B/lane),
//            SWAR nibble-split, store to swizzled LDS [cell][row][sp][4dw],
//            sp = s_local ^ (row&7)  (phase-1 writes: 2-way conflicts = free).
//   phase 2: per half-wave, one (stage, cell) -> 512B contiguous global run.
// k-permutation per (row,stage): packed byte b (0..31), nibble nb ->
//   cell = ((b>>2)&1)*2 + nb, dword = b>>3, bytelane = b&3.   (bijective,
//   identical for A and B => MFMA dot product unaffected.)
#define ROWS_PB 32
#define SGRP    16

__global__ __launch_bounds__(256) void unpack_tiles3(
    const int* __restrict__ xa, const int* __restrict__ xw,
    uint8_t* __restrict__ wsa, uint8_t* __restrict__ wsb)
{
  __shared__ __align__(16) uint32_t lds[8192];   // 32 KB
  const int sg  = blockIdx.x;        // stage group 0..3 (16 stages each)
  const int yb  = blockIdx.y;        // A: [0,128)  B: [128,472)
  const int tid = threadIdx.x;

  const int* srcBase; uint8_t* dstBase; int cellStride, chunkStride;
  if (yb < T_DIM / ROWS_PB) {
    srcBase = xa + (size_t)yb * ROWS_PB * KP + sg * SGRP * 32;
    dstBase = wsa + ((size_t)(yb >> 2) * STAGES + sg * SGRP) * CHUNK_A
                  + (size_t)(yb & 3) * (ROWS_PB * 16);
    cellStride = 2048; chunkStride = CHUNK_A;
  } else {
    const int zb = yb - T_DIM / ROWS_PB;         // 0..343
    srcBase = xw + (size_t)zb * ROWS_PB * KP + sg * SGRP * 32;
    dstBase = wsb + ((size_t)(zb >> 3) * STAGES + sg * SGRP) * CHUNK_B
                  + (size_t)(zb & 7) * (ROWS_PB * 16);
    cellStride = 4096; chunkStride = CHUNK_B;
  }

  // ---- phase 1: global (coalesced) -> LDS (swizzled) ----
  const int lq    = tid & 127;       // 128 threads cover one 2KB row-slice
  const int rhalf = tid >> 7;        // which of the 2 rows per iteration
  const int sl    = lq >> 3;         // stage-local 0..15
  const int tg    = lq & 7;          // byte-group 0..7 (4 packed bytes each)
  const int cellL = (tg & 1) * 2;
  const int dsl   = tg >> 1;         // dword slot 0..3
#pragma unroll
  for (int it = 0; it < 16; ++it) {
    const int row = it * 2 + rhalf;
    const int4 v = *(const int4*)(srcBase + (size_t)row * KP + lq * 4);
    const uint32_t p = pack4(v);
    const int sp = sl ^ (row & 7);
    uint32_t* b = &lds[(((cellL * 32 + row) << 4) + sp) * 4 + dsl];
    b[0]    = nib_lo_s8(p);          // cell cellL
    b[2048] = nib_hi_s8(p);          // cell cellL+1  (+32*16*4 dwords)
  }
  __syncthreads();

  // ---- phase 2: LDS -> workspace, 512B contiguous runs per half-wave ----
  const int row2 = tid & 31;
#pragma unroll
  for (int it = 0; it < 8; ++it) {
    const int pr = it * 8 + (tid >> 5);          // 0..63 = (stage,cell) pair
    const int s2 = pr >> 2, cl = pr & 3;
    const int sp = s2 ^ (row2 & 7);
    const uint4 v = *(const uint4*)&lds[(((cl * 32 + row2) << 4) + sp) * 4];
    *(uint4*)(dstBase + (size_t)s2 * chunkStride + cl * cellStride + row2 * 16) = v;
  }
}

// ------ i8 GEMM v2: 8 waves, 64x64/wave, 3-buffer DMA + manual vmcnt ------
__device__ __forceinline__ void dma16(const uint8_t* g, uint8_t* l) {
  __builtin_amdgcn_global_load_lds(
      (const __attribute__((address_space(1))) uint32_t*)g,
      (__attribute__((address_space(3))) uint32_t*)l, 16, 0, 0);
}

__global__ __launch_bounds__(512, 4) void gemm_i8_tb2(
    const uint8_t* __restrict__ wsa, const uint8_t* __restrict__ wsb,
    const float* __restrict__ sx, const float* __restrict__ sw,
    float* __restrict__ out)
{
  __shared__ __align__(16) uint8_t sAmem[3 * CHUNK_A];   // 24 KB
  __shared__ __align__(16) uint8_t sBmem[3 * CHUNK_B];   // 48 KB

  const int tid  = threadIdx.x;
  const int lane = tid & 63;
  const int wv   = tid >> 6;           // 8 waves, 2(M) x 4(N)
  const int wm   = wv >> 2, wn = wv & 3;
  const int h    = lane >> 5;          // k-half of the 32x32x32 MFMA
  const int ml   = lane & 31;
  const int pp   = blockIdx.x;         // A panel (32)
  const int qq   = blockIdx.y;         // B panel (43)

  const uint8_t* chunkA = wsa + (size_t)pp * STAGES * CHUNK_A;
  const uint8_t* chunkB = wsb + (size_t)qq * STAGES * CHUNK_B;
  const int laneOff = lane * 16;
  const int aOffW   = wv * 1024;       // A: 8KB / 8 waves
  const int bOffW   = wv * 2048;       // B: 16KB / 8 waves

  const int rowA = (wm * 64 + ml) * 16;       // byte offset inside a cell
  const int rowB = (wn * 64 + ml) * 16;

  int32x16 acc[2][2];
#pragma unroll
  for (int mi = 0; mi < 2; ++mi)
#pragma unroll
    for (int ni = 0; ni < 2; ++ni)
#pragma unroll
      for (int i = 0; i < 16; ++i) acc[mi][ni][i] = 0;

  // Exactly 3 global_load_lds per wave per call — vmcnt bookkeeping exact.
  auto dma_stage = [&](int s, int buf) {
    const uint8_t* ca = chunkA + (size_t)s * CHUNK_A;
    const uint8_t* cb = chunkB + (size_t)s * CHUNK_B;
    uint8_t* la = sAmem + buf * CHUNK_A;
    uint8_t* lb = sBmem + buf * CHUNK_B;
    dma16(ca + aOffW + laneOff,        la + aOffW);
    dma16(cb + bOffW + laneOff,        lb + bOffW);
    dma16(cb + bOffW + 1024 + laneOff, lb + bOffW + 1024);
  };

  dma_stage(0, 0);                     // prologue: stages 0,1 in flight (6)
  dma_stage(1, 1);

  int rb = 0;                          // read buffer  = s % 3
  int wb = 2;                          // write buffer = (s+2) % 3
#pragma unroll 1
  for (int s = 0; s < STAGES; ++s) {
    // Drain DMA(s) only; keep DMA(s+1) (3 newest) in flight across barrier.
    if (s < STAGES - 1) asm volatile("s_waitcnt vmcnt(3)" ::: "memory");
    else                asm volatile("s_waitcnt vmcnt(0)" ::: "memory");
    __builtin_amdgcn_s_barrier();      // raw barrier: no compiler vmcnt(0) drain
    // Safe: buffer wb was last read at stage s-1; all waves passed the barrier
    // above, so those ds_reads (consumed by MFMAs before it) are complete.
    if (s + 2 < STAGES) dma_stage(s + 2, wb);

    const uint8_t* baseA = sAmem + rb * CHUNK_A;
    const uint8_t* baseB = sBmem + rb * CHUNK_B;
#pragma unroll
    for (int s2 = 0; s2 < 2; ++s2) {   // two K=32 MFMA steps
      const int c = 2 * s2 + h;
      const uint8_t* pa = baseA + c * 2048 + rowA;
      const uint8_t* pb = baseB + c * 4096 + rowB;
      int32x4 aF[2], bF[2];
#pragma unroll
      for (int mi = 0; mi < 2; ++mi) aF[mi] = *(const int32x4*)(pa + mi * 512);
#pragma unroll
      for (int ni = 0; ni < 2; ++ni) bF[ni] = *(const int32x4*)(pb + ni * 512);
      __builtin_amdgcn_s_setprio(1);
#pragma unroll
      for (int mi = 0; mi < 2; ++mi)
#pragma unroll
        for (int ni = 0; ni < 2; ++ni)
          acc[mi][ni] = __builtin_amdgcn_mfma_i32_32x32x32_i8(
              aF[mi], bF[ni], acc[mi][ni], 0, 0, 0);
      __builtin_amdgcn_s_setprio(0);
    }
    rb = (rb == 2) ? 0 : rb + 1;       // rotate buffers
    wb = (wb == 2) ? 0 : wb + 1;
  }

  // epilogue: C/D (verified): col = lane&31, row = (reg&3) + 8*(reg>>2) + 4*(lane>>5)
#pragma unroll
  for (int mi = 0; mi < 2; ++mi) {
    const int rbase = pp * BM + wm * 64 + mi * 32 + 4 * h;
    float sxv[16];
#pragma unroll
    for (int r = 0; r < 16; ++r) sxv[r] = sx[rbase + (r & 3) + 8 * (r >> 2)];
#pragma unroll
    for (int ni = 0; ni < 2; ++ni) {
      const int gcol = qq * BN + wn * 64 + ni * 32 + ml;
      const float swv = sw[gcol];
#pragma unroll
      for (int r = 0; r < 16; ++r) {
        const int grow = rbase + (r & 3) + 8 * (r >> 2);
        const float v = (float)acc[mi][ni][r] * sxv[r] * swv;  // ref mul order
        out[(size_t)grow * N_DIM + gcol] = __half2float(__float2half(v));
      }
    }
  }
}

// ================= fallback (round-3, proven): f16 MFMA paths =================
__global__ __launch_bounds__(256) void repack_int32_to_bytes(
    const int* __restrict__ xa, const int* __restrict__ xw,
    uint32_t* __restrict__ da, uint32_t* __restrict__ dw)
{
  const size_t i = (size_t)blockIdx.x * blockDim.x + threadIdx.x;
  const size_t na4 = NA_BYTES / 4;
  const int4* src; uint32_t* dst; size_t off;
  if (i < na4) { src = (const int4*)xa; dst = da; off = i; }
  else         { src = (const int4*)xw; dst = dw; off = i - na4; }
  const int4 v = src[off];
  dst[off] = pack4(v);
}

__device__ __forceinline__ uint32_t cvt2(uint32_t m) {
  union U { uint32_t u; f16x2 h; } a, b, c;
  a.u = m ^ 0x64086408u; b.u = 0xE408E408u; c.h = a.h + b.h;
  return c.u;
}
__device__ __forceinline__ void unpack_cell(uint32_t* cell, uint32_t p) {
  cell[0] = cvt2( p        & 0x000F000Fu);
  cell[1] = cvt2((p >> 4)  & 0x000F000Fu);
  cell[2] = cvt2((p >> 8)  & 0x000F000Fu);
  cell[3] = cvt2((p >> 12) & 0x000F000Fu);
}

template <bool PACKED>
__global__ __launch_bounds__(256) void linear4bit_f16(
    const uint8_t* __restrict__ pqx, const float* __restrict__ sx,
    const uint8_t* __restrict__ wq,  const float* __restrict__ sw,
    const int* __restrict__ pqx32,   const int* __restrict__ wq32,
    float* __restrict__ out)
{
  __shared__ uint32_t sAf[8][128][4];
  __shared__ uint32_t sBf[8][128][4];
  const int tid = threadIdx.x, lane = tid & 63, wv = tid >> 6;
  const int wm = wv >> 1, wn = wv & 1, qd = lane >> 4, m16 = lane & 15;
  const int bm0 = blockIdx.x * 128, bn0 = blockIdx.y * 128;
  const int srow = tid >> 1, sh = tid & 1;
  const uint8_t* aPtr = pqx + (size_t)(bm0 + srow) * KP + sh * 16;
  const uint8_t* bPtr = wq  + (size_t)(bn0 + srow) * KP + sh * 16;
  const int* aPtr32 = pqx32 + (size_t)(bm0 + srow) * KP + sh * 16;
  const int* bPtr32 = wq32  + (size_t)(bn0 + srow) * KP + sh * 16;
  floatx4 acc[4][4];
#pragma unroll
  for (int mi = 0; mi < 4; ++mi)
#pragma unroll
    for (int ni = 0; ni < 4; ++ni)
#pragma unroll
      for (int r = 0; r < 4; ++r) acc[mi][ni][r] = 0.0f;
  uint4 ar, br;
  auto load_stage = [&](int s) {
    if (PACKED) {
      ar = *(const uint4*)(aPtr + (size_t)s * 32);
      br = *(const uint4*)(bPtr + (size_t)s * 32);
    } else {
      const int4* a4 = (const int4*)(aPtr32 + (size_t)s * 32);
      const int4* b4 = (const int4*)(bPtr32 + (size_t)s * 32);
      ar.x = pack4(a4[0]); ar.y = pack4(a4[1]); ar.z = pack4(a4[2]); ar.w = pack4(a4[3]);
      br.x = pack4(b4[0]); br.y = pack4(b4[1]); br.z = pack4(b4[2]); br.w = pack4(b4[3]);
    }
  };
  auto stage_to_lds = [&]() {
    uint32_t pa[4] = {ar.x, ar.y, ar.z, ar.w};
    uint32_t pb[4] = {br.x, br.y, br.z, br.w};
#pragma unroll
    for (int i = 0; i < 4; ++i) {
      unpack_cell(&sAf[4 * sh + i][srow][0], pa[i]);
      unpack_cell(&sBf[4 * sh + i][srow][0], pb[i]);
    }
  };
  load_stage(0); stage_to_lds();
#pragma unroll 1
  for (int s = 0; s < STAGES; ++s) {
    __syncthreads();
    if (s + 1 < STAGES) load_stage(s + 1);
#pragma unroll
    for (int s2 = 0; s2 < 2; ++s2) {
      f16x8 aF[4], bF[4];
#pragma unroll
      for (int mi = 0; mi < 4; ++mi)
        aF[mi] = *(const f16x8*)&sAf[4 * s2 + qd][wm * 64 + mi * 16 + m16][0];
#pragma unroll
      for (int ni = 0; ni < 4; ++ni)
        bF[ni] = *(const f16x8*)&sBf[4 * s2 + qd][wn * 64 + ni * 16 + m16][0];
#pragma unroll
      for (int mi = 0; mi < 4; ++mi)
#pragma unroll
        for (int ni = 0; ni < 4; ++ni)
          acc[mi][ni] = __builtin_amdgcn_mfma_f32_16x16x32_f16(aF[mi], bF[ni], acc[mi][ni], 0, 0, 0);
    }
    __syncthreads();
    if (s + 1 < STAGES) stage_to_lds();
  }
#pragma unroll
  for (int mi = 0; mi < 4; ++mi) {
    const int grow0 = bm0 + wm * 64 + mi * 16 + qd * 4;
    const float s0 = sx[grow0], s1 = sx[grow0 + 1], s2v = sx[grow0 + 2], s3 = sx[grow0 + 3];
#pragma unroll
    for (int ni = 0; ni < 4; ++ni) {
      const int gcol = bn0 + wn * 64 + ni * 16 + m16;
      const float swv = sw[gcol];
      const floatx4 a = acc[mi][ni];
      out[(size_t)(grow0 + 0) * N_DIM + gcol] = __half2float(__float2half(a[0] * s0 * swv));
      out[(size_t)(grow0 + 1) * N_DIM + gcol] = __half2float(__float2half(a[1] * s1 * swv));
      out[(size_t)(grow0 + 2) * N_DIM + gcol] = __half2float(__float2half(a[2] * s2v * swv));
      out[(size_t)(grow0 + 3) * N_DIM + gcol] = __half2float(__float2half(a[3] * s3 * swv));
    }
  }
}

extern "C" void kernel_launch(void* const* d_in, const int* in_sizes, int n_in,
                              void* d_out, int out_size, void* d_ws, size_t ws_size,
                              hipStream_t stream) {
  const int*   pqx32 = (const int*)d_in[0];   // [4096*2048] int32 (one per packed byte)
  const float* sxp   = (const float*)d_in[1]; // [4096]
  const int*   wq32  = (const int*)d_in[2];   // [11008*2048] int32
  const float* swp   = (const float*)d_in[3]; // [11008]
  float* outp = (float*)d_out;                // [4096, 11008] fp32 (fp16-rounded)

  if (ws_size >= WS_A + WS_B) {
    uint8_t* wsa = (uint8_t*)d_ws;
    uint8_t* wsb = wsa + WS_A;
    unpack_tiles3<<<dim3(STAGES / SGRP, T_DIM / ROWS_PB + N_DIM / ROWS_PB), 256, 0, stream>>>(
        pqx32, wq32, wsa, wsb);
    gemm_i8_tb2<<<dim3(A_PANELS, B_PANELS), 512, 0, stream>>>(wsa, wsb, sxp, swp, outp);
  } else if (ws_size >= NA_BYTES + NW_BYTES) {
    uint8_t* da = (uint8_t*)d_ws;
    uint8_t* dw = da + NA_BYTES;
    const size_t total4 = (NA_BYTES + NW_BYTES) / 4;
    repack_int32_to_bytes<<<(uint32_t)(total4 / 256), 256, 0, stream>>>(
        pqx32, wq32, (uint32_t*)da, (uint32_t*)dw);
    linear4bit_f16<true><<<dim3(T_DIM / 128, N_DIM / 128), 256, 0, stream>>>(
        da, sxp, dw, swp, nullptr, nullptr, outp);
  } else {
    linear4bit_f16<false><<<dim3(T_DIM / 128, N_DIM / 128), 256, 0, stream>>>(
        nullptr, sxp, nullptr, swp, pqx32, wq32, outp);
  }
}